// Round 5
// baseline (451.054 us; speedup 1.0000x reference)
//
#include <hip/hip_runtime.h>

// ---------------------------------------------------------------------------
// SelfAttention: out = softmax((x@Wk+bk) @ (x@Wq+bq)^T) @ (x@Wv+bv)
// B=4, N=2048, E=A=1024, fp32 in/out.
// R4b: all-fp16 pipeline (fixed call-site arity from R4).
//   k/q proj: 2-term fp16 split of x (x=xh+xl), W single fp16. fp16 products
//             are exact in fp32 acc, so error = W rounding + out rounding.
//   v proj, scores, PV: 1-term fp16.
//   GEMM core: block 128x128, 2 waves, wave tile 64x128 -> per K=32 iter:
//   12 ds_read_b128 (144cy) vs 32 MFMA (154cy) = MFMA-bound (was 8 vs 16).
// ---------------------------------------------------------------------------

typedef __attribute__((ext_vector_type(8))) _Float16 half8;   // 4 VGPRs
typedef __attribute__((ext_vector_type(4))) float floatx4;

#define BK 32

static __device__ __forceinline__ unsigned short f2h(float f) {
    _Float16 h = (_Float16)f;          // RNE
    return *(unsigned short*)&h;
}
static __device__ __forceinline__ float h2f(unsigned short u) {
    _Float16 h = *(_Float16*)&u;
    return (float)h;
}

// async global->LDS, 16B per lane; LDS dst = wave-uniform base + lane*16
static __device__ __forceinline__ void gll16(const unsigned short* g,
                                             unsigned short* l) {
    __builtin_amdgcn_global_load_lds(
        (__attribute__((address_space(1))) void*)(g),
        (__attribute__((address_space(3))) void*)(l), 16, 0, 0);
}

// ---------------------------------------------------------------------------
// split fp32 -> fp16 hi + fp16 lo (elementwise, n % 4 == 0)
// ---------------------------------------------------------------------------
__global__ void split_f32(const float* __restrict__ src,
                          unsigned short* __restrict__ hi,
                          unsigned short* __restrict__ lo, int n) {
    int i = (blockIdx.x * blockDim.x + threadIdx.x) * 4;
    if (i >= n) return;
    float4 f = *(const float4*)(src + i);
    float v[4] = {f.x, f.y, f.z, f.w};
    unsigned short hh[4], ll[4];
#pragma unroll
    for (int j = 0; j < 4; ++j) {
        hh[j] = f2h(v[j]);
        ll[j] = f2h(v[j] - h2f(hh[j]));
    }
    *(ushort4*)(hi + i) = make_ushort4(hh[0], hh[1], hh[2], hh[3]);
    *(ushort4*)(lo + i) = make_ushort4(ll[0], ll[1], ll[2], ll[3]);
}

// ---------------------------------------------------------------------------
// Wz [R][C] fp32 -> T + z*R*C = Wz^T [C][R] fp16, z = 0,1,2 (Wk, Wq, Wv)
// ---------------------------------------------------------------------------
__global__ void splitT_w3(const float* __restrict__ W0,
                          const float* __restrict__ W1,
                          const float* __restrict__ W2,
                          unsigned short* __restrict__ T, int R, int C) {
    __shared__ float tile[32][33];
    const float* W = blockIdx.z == 0 ? W0 : (blockIdx.z == 1 ? W1 : W2);
    unsigned short* Tz = T + (size_t)blockIdx.z * R * C;
    int tx = threadIdx.x & 31, ty = threadIdx.x >> 5;   // 32 x 8
    int c0 = blockIdx.x * 32, r0 = blockIdx.y * 32;
#pragma unroll
    for (int j = 0; j < 32; j += 8)
        tile[ty + j][tx] = W[(long long)(r0 + ty + j) * C + c0 + tx];
    __syncthreads();
#pragma unroll
    for (int j = 0; j < 32; j += 8)
        Tz[(long long)(c0 + ty + j) * R + r0 + tx] = f2h(tile[tx][ty + j]);
}

// ---------------------------------------------------------------------------
// 16-bit transpose: src [z][R][C] -> dst [z][C][R]
// ---------------------------------------------------------------------------
__global__ void transpose_bf(const unsigned short* __restrict__ src,
                             unsigned short* __restrict__ dst, int R, int C) {
    __shared__ unsigned short tile[32][33];
    long long zs = (long long)blockIdx.z * R * C;
    int tx = threadIdx.x & 31, ty = threadIdx.x >> 5;
    int c0 = blockIdx.x * 32, r0 = blockIdx.y * 32;
#pragma unroll
    for (int j = 0; j < 32; j += 8)
        tile[ty + j][tx] = src[zs + (long long)(r0 + ty + j) * C + c0 + tx];
    __syncthreads();
#pragma unroll
    for (int j = 0; j < 32; j += 8)
        dst[zs + (long long)(c0 + ty + j) * R + r0 + tx] = tile[tx][ty + j];
}

// ---------------------------------------------------------------------------
// NT GEMM: C[M,N] = A[M,K] * B[N,K]^T (+bias[col]); fp16 in, fp32 acc.
// TERMS=2: A = Ah + Al (fp16 split), B single -> exact-x 2-term product.
// Block 128x128, 128 threads (2 waves), wave tile 64 rows x 128 cols.
// mode 0: fp32 -> Cf; else fp16 -> Ch.
// LDS: unpadded [row][32] tiles (global_load_lds needs lane-contiguous dst);
// bank conflicts broken by XOR chunk swizzle, symmetric at stage & read
// (verified conflict-free in R2 rocprof).
// ---------------------------------------------------------------------------
template <int TERMS>
__global__ __launch_bounds__(128)
void gemm_nt(const unsigned short* __restrict__ Ah,
             const unsigned short* __restrict__ Al,
             const unsigned short* __restrict__ B,
             const float* __restrict__ bias,
             float* __restrict__ Cf,
             unsigned short* __restrict__ Ch,
             int mode, int M, int N, int K,
             long long sA, long long sB, long long sC) {
    __shared__ unsigned short smem[(TERMS + 1) * 128 * BK];
    unsigned short* As_h = smem;
    unsigned short* As_l = smem + 128 * BK;                    // TERMS==2 only
    unsigned short* Bs   = smem + TERMS * 128 * BK;

    const int tid = threadIdx.x;
    const int lane = tid & 63;
    const int wave = tid >> 6;          // 0/1
    const int quad = lane >> 4;
    const int l15 = lane & 15;

    const long long zA = (long long)blockIdx.z * sA;
    const long long zB = (long long)blockIdx.z * sB;
    const long long zC = (long long)blockIdx.z * sC;
    const int m0 = blockIdx.y * 128;
    const int n0 = blockIdx.x * 128;

    // staging: wave w covers tile rows [64w, 64w+64) of A and B, 4 insts of
    // 16 rows each. lane i: row i>>2, chunk pos (i&3) holds global chunk
    // (i&3) ^ ((row>>1)&3)   [16-row-periodic XOR swizzle]
    const int srow = wave * 64 + (lane >> 2);
    const int schunk8 = (((lane & 3) ^ ((lane >> 3) & 3)) << 3);
    const long long aoff = zA + (long long)(m0 + srow) * K + schunk8;
    const long long boff = zB + (long long)(n0 + srow) * K + schunk8;
    unsigned short* lA = As_h + (wave * 64) * BK;
    unsigned short* lAl = As_l + (wave * 64) * BK;
    unsigned short* lB = Bs + (wave * 64) * BK;

    floatx4 zero = {0.f, 0.f, 0.f, 0.f};
    floatx4 acc[4][8];
#pragma unroll
    for (int i = 0; i < 4; ++i)
#pragma unroll
        for (int j = 0; j < 8; ++j) acc[i][j] = zero;

    for (int k0 = 0; k0 < K; k0 += BK) {
        __syncthreads();
#pragma unroll
        for (int j = 0; j < 4; ++j) {
            gll16(Ah + aoff + k0 + (long long)j * 16 * K, lA + j * 16 * BK);
            if (TERMS == 2)
                gll16(Al + aoff + k0 + (long long)j * 16 * K, lAl + j * 16 * BK);
            gll16(B + boff + k0 + (long long)j * 16 * K, lB + j * 16 * BK);
        }
        __syncthreads();

        half8 a_h[4], a_l[4], b[8];
#pragma unroll
        for (int mi = 0; mi < 4; ++mi) {
            int r = wave * 64 + mi * 16 + l15;
            int off = r * BK + (((quad ^ (r >> 1)) & 3) << 3);
            a_h[mi] = *(const half8*)&As_h[off];
            if (TERMS == 2) a_l[mi] = *(const half8*)&As_l[off];
        }
#pragma unroll
        for (int ni = 0; ni < 8; ++ni) {
            int r = ni * 16 + l15;
            int off = r * BK + (((quad ^ (r >> 1)) & 3) << 3);
            b[ni] = *(const half8*)&Bs[off];
        }
#pragma unroll
        for (int mi = 0; mi < 4; ++mi)
#pragma unroll
            for (int ni = 0; ni < 8; ++ni) {
                acc[mi][ni] = __builtin_amdgcn_mfma_f32_16x16x32_f16(
                    a_h[mi], b[ni], acc[mi][ni], 0, 0, 0);
                if (TERMS == 2)
                    acc[mi][ni] = __builtin_amdgcn_mfma_f32_16x16x32_f16(
                        a_l[mi], b[ni], acc[mi][ni], 0, 0, 0);
            }
    }

    // epilogue: C/D layout col=lane&15, row=quad*4+reg  [verified m89/m91]
#pragma unroll
    for (int mi = 0; mi < 4; ++mi)
#pragma unroll
        for (int ni = 0; ni < 8; ++ni) {
            int colg = n0 + ni * 16 + l15;
            float bv = bias ? bias[colg] : 0.f;
#pragma unroll
            for (int r = 0; r < 4; ++r) {
                int rowg = m0 + wave * 64 + mi * 16 + quad * 4 + r;
                float v = acc[mi][ni][r] + bv;
                long long idx = zC + (long long)rowg * N + colg;
                if (mode == 0) Cf[idx] = v;
                else           Ch[idx] = f2h(v);
            }
        }
}

// ---------------------------------------------------------------------------
// row softmax: S [rows][cols] fp32 -> P fp16.  One block per row, cols=2048.
// ---------------------------------------------------------------------------
__global__ __launch_bounds__(256)
void softmax_rows(const float* __restrict__ S, unsigned short* __restrict__ P,
                  int cols) {
    __shared__ float red_m[4];
    __shared__ float red_s[4];
    const long long row = blockIdx.x;
    const float* s = S + row * cols;
    unsigned short* p = P + row * cols;
    const int tid = threadIdx.x;
    const int lane = tid & 63;
    const int wave = tid >> 6;

    float4 v0 = *(const float4*)(s + tid * 8);
    float4 v1 = *(const float4*)(s + tid * 8 + 4);
    float vals[8] = {v0.x, v0.y, v0.z, v0.w, v1.x, v1.y, v1.z, v1.w};

    float m = vals[0];
#pragma unroll
    for (int i = 1; i < 8; ++i) m = fmaxf(m, vals[i]);
#pragma unroll
    for (int off = 32; off >= 1; off >>= 1) m = fmaxf(m, __shfl_xor(m, off));
    if (lane == 0) red_m[wave] = m;
    __syncthreads();
    m = fmaxf(fmaxf(red_m[0], red_m[1]), fmaxf(red_m[2], red_m[3]));

    float e[8];
    float sum = 0.f;
#pragma unroll
    for (int i = 0; i < 8; ++i) {
        e[i] = __expf(vals[i] - m);
        sum += e[i];
    }
#pragma unroll
    for (int off = 32; off >= 1; off >>= 1) sum += __shfl_xor(sum, off);
    if (lane == 0) red_s[wave] = sum;
    __syncthreads();
    sum = red_s[0] + red_s[1] + red_s[2] + red_s[3];
    float inv = 1.0f / sum;

    unsigned short ob[8];
#pragma unroll
    for (int i = 0; i < 8; ++i) ob[i] = f2h(e[i] * inv);
    *(ushort4*)(p + tid * 8)     = make_ushort4(ob[0], ob[1], ob[2], ob[3]);
    *(ushort4*)(p + tid * 8 + 4) = make_ushort4(ob[4], ob[5], ob[6], ob[7]);
}

// ---------------------------------------------------------------------------
extern "C" void kernel_launch(void* const* d_in, const int* in_sizes, int n_in,
                              void* d_out, int out_size, void* d_ws,
                              size_t ws_size, hipStream_t stream) {
    const float* x  = (const float*)d_in[0];
    const float* Wk = (const float*)d_in[1];
    const float* bk = (const float*)d_in[2];
    const float* Wq = (const float*)d_in[3];
    const float* bq = (const float*)d_in[4];
    const float* Wv = (const float*)d_in[5];
    const float* bv = (const float*)d_in[6];
    float* out = (float*)d_out;

    const int Bb = 4, Ns = 2048, E = 1024, Aa = 1024;
    const int M = Bb * Ns;  // 8192

    char* p = (char*)d_ws;
    auto alloc = [&](size_t bytes) {
        char* r = p;
        p += (bytes + 255) & ~(size_t)255;
        return r;
    };
    const size_t MA = (size_t)M * Aa;          // 8.39M elems
    unsigned short* xh  = (unsigned short*)alloc(MA * 2);
    unsigned short* xl  = (unsigned short*)alloc(MA * 2);   // contiguous w/ xh
    unsigned short* WT  = (unsigned short*)alloc((size_t)3 * E * Aa * 2);
    unsigned short* k16 = (unsigned short*)alloc(MA * 2);
    unsigned short* q16 = (unsigned short*)alloc(MA * 2);
    unsigned short* v16 = (unsigned short*)alloc(MA * 2);
    unsigned short* vT  = (unsigned short*)alloc(MA * 2);
    float* scores = (float*)alloc((size_t)Bb * Ns * Ns * 4);
    // attn (fp16, 33.5MB) overlays xh+xl (16.8+16.8MB contiguous), dead by
    // the time softmax runs
    unsigned short* attn = xh;

    // 1. split x -> fp16 hi/lo; W^T -> fp16 (all three in one launch)
    split_f32<<<(int)(MA / 4 / 256), 256, 0, stream>>>(x, xh, xl, (int)MA);
    splitT_w3<<<dim3(Aa / 32, E / 32, 3), 256, 0, stream>>>(Wk, Wq, Wv, WT, E, Aa);

    // 2. projections: k/q 2-term fp16 split -> fp16 out; v 1-term fp16
    dim3 g1(Aa / 128, M / 128, 1);
    gemm_nt<2><<<g1, 128, 0, stream>>>(xh, xl, WT, bk, nullptr, k16, 1,
                                       M, Aa, E, 0, 0, 0);
    gemm_nt<2><<<g1, 128, 0, stream>>>(xh, xl, WT + (size_t)E * Aa, bq, nullptr,
                                       q16, 1, M, Aa, E, 0, 0, 0);
    gemm_nt<1><<<g1, 128, 0, stream>>>(xh, nullptr, WT + (size_t)2 * E * Aa, bv,
                                       nullptr, v16, 1, M, Aa, E, 0, 0, 0);

    // 3. scores[b,n,m] = k[b,n,:] . q[b,m,:]   (batched NT fp16, fp32 out)
    dim3 g2(Ns / 128, Ns / 128, Bb);
    gemm_nt<1><<<g2, 128, 0, stream>>>(
        k16, nullptr, q16, nullptr, scores, nullptr, 0, Ns, Ns, Aa,
        (long long)Ns * Aa, (long long)Ns * Aa, (long long)Ns * Ns);

    // 4. softmax rows -> fp16 attn
    softmax_rows<<<M, 256, 0, stream>>>(scores, attn, Ns);

    // 5. v -> v^T (so attn@v is NT with contiguous K=m)
    transpose_bf<<<dim3(Aa / 32, Ns / 32, Bb), 256, 0, stream>>>(v16, vT, Ns, Aa);

    // 6. out[b,n,a] = sum_m attn[b,n,m] * vT[b,a,m]
    dim3 g3(Aa / 128, Ns / 128, Bb);
    gemm_nt<1><<<g3, 128, 0, stream>>>(
        attn, nullptr, vT, nullptr, out, nullptr, 0, Ns, Aa, Ns,
        (long long)Ns * Ns, (long long)Aa * Ns, (long long)Ns * Aa);
}

// Round 6
// 341.844 us; speedup vs baseline: 1.3195x; 1.3195x over previous
//
#include <hip/hip_runtime.h>

// ---------------------------------------------------------------------------
// SelfAttention: out = softmax((x@Wk+bk) @ (x@Wq+bq)^T) @ (x@Wv+bv)
// B=4, N=2048, E=A=1024, fp32 in/out.
// R6: all-fp16; 256-thread 128x128 blocks (R4's 128-thread config halved
// waves/CU and regressed); BK=64 (half the barrier drains); all three
// projections fused into one M=8192 x N=3072 2-term GEMM with segmented
// epilogue. Numerics: k/q/v = x_hi@W + x_lo@W (fp16 products exact in fp32
// acc); scores/PV 1-term fp16.
// ---------------------------------------------------------------------------

typedef __attribute__((ext_vector_type(8))) _Float16 half8;   // 4 VGPRs
typedef __attribute__((ext_vector_type(4))) float floatx4;

#define BK 64

static __device__ __forceinline__ unsigned short f2h(float f) {
    _Float16 h = (_Float16)f;          // RNE
    return *(unsigned short*)&h;
}
static __device__ __forceinline__ float h2f(unsigned short u) {
    _Float16 h = *(_Float16*)&u;
    return (float)h;
}

// async global->LDS, 16B per lane; LDS dst = wave-uniform base + lane*16
static __device__ __forceinline__ void gll16(const unsigned short* g,
                                             unsigned short* l) {
    __builtin_amdgcn_global_load_lds(
        (__attribute__((address_space(1))) void*)(g),
        (__attribute__((address_space(3))) void*)(l), 16, 0, 0);
}

// ---------------------------------------------------------------------------
// split fp32 -> fp16 hi + fp16 lo (elementwise, n % 4 == 0)
// ---------------------------------------------------------------------------
__global__ void split_f32(const float* __restrict__ src,
                          unsigned short* __restrict__ hi,
                          unsigned short* __restrict__ lo, int n) {
    int i = (blockIdx.x * blockDim.x + threadIdx.x) * 4;
    if (i >= n) return;
    float4 f = *(const float4*)(src + i);
    float v[4] = {f.x, f.y, f.z, f.w};
    unsigned short hh[4], ll[4];
#pragma unroll
    for (int j = 0; j < 4; ++j) {
        hh[j] = f2h(v[j]);
        ll[j] = f2h(v[j] - h2f(hh[j]));
    }
    *(ushort4*)(hi + i) = make_ushort4(hh[0], hh[1], hh[2], hh[3]);
    *(ushort4*)(lo + i) = make_ushort4(ll[0], ll[1], ll[2], ll[3]);
}

// ---------------------------------------------------------------------------
// Wz [R][C] fp32 -> T + z*R*C = Wz^T [C][R] fp16, z = 0,1,2 (Wk, Wq, Wv)
// ---------------------------------------------------------------------------
__global__ void splitT_w3(const float* __restrict__ W0,
                          const float* __restrict__ W1,
                          const float* __restrict__ W2,
                          unsigned short* __restrict__ T, int R, int C) {
    __shared__ float tile[32][33];
    const float* W = blockIdx.z == 0 ? W0 : (blockIdx.z == 1 ? W1 : W2);
    unsigned short* Tz = T + (size_t)blockIdx.z * R * C;
    int tx = threadIdx.x & 31, ty = threadIdx.x >> 5;   // 32 x 8
    int c0 = blockIdx.x * 32, r0 = blockIdx.y * 32;
#pragma unroll
    for (int j = 0; j < 32; j += 8)
        tile[ty + j][tx] = W[(long long)(r0 + ty + j) * C + c0 + tx];
    __syncthreads();
#pragma unroll
    for (int j = 0; j < 32; j += 8)
        Tz[(long long)(c0 + ty + j) * R + r0 + tx] = f2h(tile[tx][ty + j]);
}

// ---------------------------------------------------------------------------
// bias3[i] = concat(b0,b1,b2)[i], i < 3072
// ---------------------------------------------------------------------------
__global__ void bias_concat(const float* __restrict__ b0,
                            const float* __restrict__ b1,
                            const float* __restrict__ b2,
                            float* __restrict__ dst) {
    int i = blockIdx.x * blockDim.x + threadIdx.x;
    int s = i >> 10;
    const float* b = s == 0 ? b0 : (s == 1 ? b1 : b2);
    dst[i] = b[i & 1023];
}

// ---------------------------------------------------------------------------
// 16-bit transpose: src [z][R][C] -> dst [z][C][R]
// ---------------------------------------------------------------------------
__global__ void transpose_bf(const unsigned short* __restrict__ src,
                             unsigned short* __restrict__ dst, int R, int C) {
    __shared__ unsigned short tile[32][33];
    long long zs = (long long)blockIdx.z * R * C;
    int tx = threadIdx.x & 31, ty = threadIdx.x >> 5;
    int c0 = blockIdx.x * 32, r0 = blockIdx.y * 32;
#pragma unroll
    for (int j = 0; j < 32; j += 8)
        tile[ty + j][tx] = src[zs + (long long)(r0 + ty + j) * C + c0 + tx];
    __syncthreads();
#pragma unroll
    for (int j = 0; j < 32; j += 8)
        dst[zs + (long long)(c0 + ty + j) * R + r0 + tx] = tile[tx][ty + j];
}

// ---------------------------------------------------------------------------
// NT GEMM: C[M,N] = A[M,K] * B[N,K]^T (+bias[col]); fp16 in, fp32 acc.
// TERMS=2: A = Ah + Al (fp16 split), B single.
// Block 128x128, 256 threads (4 waves, 2x2 grid of 64x64 wave tiles), BK=64.
// mode 0: fp32 -> Cf[rowg*N+colg]; mode 2: fp16 segmented -> Ch, where
//   segment = colg>>10, element Ch[seg*sC + rowg*1024 + (colg&1023)].
// LDS: unpadded [row][64] tiles (128B rows = full 32-bank span).
// XOR swizzle: chunk position p of row holds global chunk p ^ (row&7);
// b128 reads then hit each bank-group with exactly 8 lanes (uniform=optimal).
// ---------------------------------------------------------------------------
template <int TERMS>
__global__ __launch_bounds__(256)
void gemm_nt(const unsigned short* __restrict__ Ah,
             const unsigned short* __restrict__ Al,
             const unsigned short* __restrict__ B,
             const float* __restrict__ bias,
             float* __restrict__ Cf,
             unsigned short* __restrict__ Ch,
             int mode, int M, int N, int K,
             long long sA, long long sB, long long sC) {
    __shared__ unsigned short smem[(TERMS + 1) * 128 * BK];
    unsigned short* As_h = smem;
    unsigned short* As_l = smem + 128 * BK;                    // TERMS==2 only
    unsigned short* Bs   = smem + TERMS * 128 * BK;

    const int tid = threadIdx.x;
    const int lane = tid & 63;
    const int wave = tid >> 6;          // 0..3
    const int quad = lane >> 4;
    const int l15 = lane & 15;
    const int wm = (wave & 1) * 64;
    const int wn = (wave >> 1) * 64;

    const long long zA = (long long)blockIdx.z * sA;
    const long long zB = (long long)blockIdx.z * sB;
    const long long zC = (long long)blockIdx.z * sC;
    const int m0 = blockIdx.y * 128;
    const int n0 = blockIdx.x * 128;

    // staging: wave w covers tile rows [32w, 32w+32) of A and B, 4 gll16 each
    // (8 rows x 128B per inst). lane i: row i>>3, position p=i&7 receives
    // global chunk p ^ (row&7).
    const int srow = wave * 32 + (lane >> 3);
    const int schunk8 = (((lane & 7) ^ ((lane >> 3) & 7)) << 3);
    const long long aoff = zA + (long long)(m0 + srow) * K + schunk8;
    const long long boff = zB + (long long)(n0 + srow) * K + schunk8;
    unsigned short* lA  = As_h + (wave * 32) * BK;
    unsigned short* lAl = As_l + (wave * 32) * BK;
    unsigned short* lB  = Bs   + (wave * 32) * BK;

    floatx4 zero = {0.f, 0.f, 0.f, 0.f};
    floatx4 acc[4][4];
#pragma unroll
    for (int i = 0; i < 4; ++i)
#pragma unroll
        for (int j = 0; j < 4; ++j) acc[i][j] = zero;

    for (int k0 = 0; k0 < K; k0 += BK) {
        __syncthreads();
#pragma unroll
        for (int j = 0; j < 4; ++j) {
            gll16(Ah + aoff + k0 + (long long)j * 8 * K, lA + j * 8 * BK);
            if (TERMS == 2)
                gll16(Al + aoff + k0 + (long long)j * 8 * K, lAl + j * 8 * BK);
            gll16(B + boff + k0 + (long long)j * 8 * K, lB + j * 8 * BK);
        }
        __syncthreads();

#pragma unroll
        for (int t = 0; t < 2; ++t) {      // two K=32 MFMA steps per BK=64
            half8 a_h[4], a_l[4], b[4];
#pragma unroll
            for (int mi = 0; mi < 4; ++mi) {
                int r = wm + mi * 16 + l15;
                int p = (t * 4 + quad) ^ (r & 7);
                a_h[mi] = *(const half8*)&As_h[r * BK + p * 8];
                if (TERMS == 2) a_l[mi] = *(const half8*)&As_l[r * BK + p * 8];
            }
#pragma unroll
            for (int ni = 0; ni < 4; ++ni) {
                int r = wn + ni * 16 + l15;
                int p = (t * 4 + quad) ^ (r & 7);
                b[ni] = *(const half8*)&Bs[r * BK + p * 8];
            }
#pragma unroll
            for (int mi = 0; mi < 4; ++mi)
#pragma unroll
                for (int ni = 0; ni < 4; ++ni) {
                    acc[mi][ni] = __builtin_amdgcn_mfma_f32_16x16x32_f16(
                        a_h[mi], b[ni], acc[mi][ni], 0, 0, 0);
                    if (TERMS == 2)
                        acc[mi][ni] = __builtin_amdgcn_mfma_f32_16x16x32_f16(
                            a_l[mi], b[ni], acc[mi][ni], 0, 0, 0);
                }
        }
    }

    // epilogue: C/D layout col=lane&15, row=quad*4+reg  [verified m89/m91]
#pragma unroll
    for (int mi = 0; mi < 4; ++mi)
#pragma unroll
        for (int ni = 0; ni < 4; ++ni) {
            int colg = n0 + wn + ni * 16 + l15;
            float bv = bias ? bias[colg] : 0.f;
#pragma unroll
            for (int r = 0; r < 4; ++r) {
                int rowg = m0 + wm + mi * 16 + quad * 4 + r;
                float v = acc[mi][ni][r] + bv;
                if (mode == 0) {
                    Cf[zC + (long long)rowg * N + colg] = v;
                } else {  // mode 2: segmented fp16 (k16|q16|v16 contiguous)
                    int seg = colg >> 10;
                    Ch[(long long)seg * sC + (long long)rowg * 1024 +
                       (colg & 1023)] = f2h(v);
                }
            }
        }
}

// ---------------------------------------------------------------------------
// row softmax: S [rows][cols] fp32 -> P fp16.  One block per row, cols=2048.
// ---------------------------------------------------------------------------
__global__ __launch_bounds__(256)
void softmax_rows(const float* __restrict__ S, unsigned short* __restrict__ P,
                  int cols) {
    __shared__ float red_m[4];
    __shared__ float red_s[4];
    const long long row = blockIdx.x;
    const float* s = S + row * cols;
    unsigned short* p = P + row * cols;
    const int tid = threadIdx.x;
    const int lane = tid & 63;
    const int wave = tid >> 6;

    float4 v0 = *(const float4*)(s + tid * 8);
    float4 v1 = *(const float4*)(s + tid * 8 + 4);
    float vals[8] = {v0.x, v0.y, v0.z, v0.w, v1.x, v1.y, v1.z, v1.w};

    float m = vals[0];
#pragma unroll
    for (int i = 1; i < 8; ++i) m = fmaxf(m, vals[i]);
#pragma unroll
    for (int off = 32; off >= 1; off >>= 1) m = fmaxf(m, __shfl_xor(m, off));
    if (lane == 0) red_m[wave] = m;
    __syncthreads();
    m = fmaxf(fmaxf(red_m[0], red_m[1]), fmaxf(red_m[2], red_m[3]));

    float e[8];
    float sum = 0.f;
#pragma unroll
    for (int i = 0; i < 8; ++i) {
        e[i] = __expf(vals[i] - m);
        sum += e[i];
    }
#pragma unroll
    for (int off = 32; off >= 1; off >>= 1) sum += __shfl_xor(sum, off);
    if (lane == 0) red_s[wave] = sum;
    __syncthreads();
    sum = red_s[0] + red_s[1] + red_s[2] + red_s[3];
    float inv = 1.0f / sum;

    unsigned short ob[8];
#pragma unroll
    for (int i = 0; i < 8; ++i) ob[i] = f2h(e[i] * inv);
    *(ushort4*)(p + tid * 8)     = make_ushort4(ob[0], ob[1], ob[2], ob[3]);
    *(ushort4*)(p + tid * 8 + 4) = make_ushort4(ob[4], ob[5], ob[6], ob[7]);
}

// ---------------------------------------------------------------------------
extern "C" void kernel_launch(void* const* d_in, const int* in_sizes, int n_in,
                              void* d_out, int out_size, void* d_ws,
                              size_t ws_size, hipStream_t stream) {
    const float* x  = (const float*)d_in[0];
    const float* Wk = (const float*)d_in[1];
    const float* bk = (const float*)d_in[2];
    const float* Wq = (const float*)d_in[3];
    const float* bq = (const float*)d_in[4];
    const float* Wv = (const float*)d_in[5];
    const float* bv = (const float*)d_in[6];
    float* out = (float*)d_out;

    const int Bb = 4, Ns = 2048, E = 1024, Aa = 1024;
    const int M = Bb * Ns;  // 8192

    char* p = (char*)d_ws;
    auto alloc = [&](size_t bytes) {
        char* r = p;
        p += (bytes + 255) & ~(size_t)255;
        return r;
    };
    const size_t MA = (size_t)M * Aa;          // 8.39M elems
    unsigned short* xh  = (unsigned short*)alloc(MA * 2);
    unsigned short* xl  = (unsigned short*)alloc(MA * 2);   // contiguous w/ xh
    unsigned short* WT  = (unsigned short*)alloc((size_t)3 * E * Aa * 2);
    // k16,q16,v16 MUST be contiguous (segmented epilogue): MA*2 is a
    // multiple of 256, so alloc() inserts no padding.
    unsigned short* k16 = (unsigned short*)alloc(MA * 2);
    unsigned short* q16 = (unsigned short*)alloc(MA * 2);
    unsigned short* v16 = (unsigned short*)alloc(MA * 2);
    unsigned short* vT  = (unsigned short*)alloc(MA * 2);
    float* bias3 = (float*)alloc(3072 * 4);
    float* scores = (float*)alloc((size_t)Bb * Ns * Ns * 4);
    // attn (fp16, 33.5MB) overlays xh+xl (contiguous, dead after projections)
    unsigned short* attn = xh;

    // 1. prep: x -> fp16 hi/lo; W^T fp16 x3; bias concat
    split_f32<<<(int)(MA / 4 / 256), 256, 0, stream>>>(x, xh, xl, (int)MA);
    splitT_w3<<<dim3(Aa / 32, E / 32, 3), 256, 0, stream>>>(Wk, Wq, Wv, WT, E, Aa);
    bias_concat<<<12, 256, 0, stream>>>(bk, bq, bv, bias3);

    // 2. fused projections: [k|q|v] = (xh+xl) @ [Wk|Wq|Wv]^T + bias3
    gemm_nt<2><<<dim3(3 * Aa / 128, M / 128, 1), 256, 0, stream>>>(
        xh, xl, WT, bias3, nullptr, k16, 2, M, 3 * Aa, E, 0, 0, (long long)MA);

    // 3. scores[b,n,m] = k[b,n,:] . q[b,m,:]   (batched NT fp16, fp32 out)
    gemm_nt<1><<<dim3(Ns / 128, Ns / 128, Bb), 256, 0, stream>>>(
        k16, nullptr, q16, nullptr, scores, nullptr, 0, Ns, Ns, Aa,
        (long long)Ns * Aa, (long long)Ns * Aa, (long long)Ns * Ns);

    // 4. softmax rows -> fp16 attn
    softmax_rows<<<M, 256, 0, stream>>>(scores, attn, Ns);

    // 5. v -> v^T (so attn@v is NT with contiguous K=m)
    transpose_bf<<<dim3(Aa / 32, Ns / 32, Bb), 256, 0, stream>>>(v16, vT, Ns, Aa);

    // 6. out[b,n,a] = sum_m attn[b,n,m] * vT[b,a,m]
    gemm_nt<1><<<dim3(Aa / 128, Ns / 128, Bb), 256, 0, stream>>>(
        attn, nullptr, vT, nullptr, out, nullptr, 0, Ns, Aa, Ns,
        (long long)Ns * Ns, (long long)Aa * Ns, (long long)Ns * Aa);
}

// Round 7
// 302.557 us; speedup vs baseline: 1.4908x; 1.1298x over previous
//
#include <hip/hip_runtime.h>

// ---------------------------------------------------------------------------
// SelfAttention: out = softmax((x@Wk+bk) @ (x@Wq+bq)^T) @ (x@Wv+bv)
// B=4, N=2048, E=A=1024, fp32 in/out.
// R7: full 1-term fp16 pipeline. R5/R6 showed absmax (0.0742) is dominated
// by k/q logit noise (W-rounding + k/q-output fp16 rounding, ~1.4e-2); the
// x_lo term only adds a third quadrature component (+14% -> ~0.085
// predicted). Dropping it halves the projection GEMM and shrinks LDS to
// 32 KB (5 blocks/CU).
// GEMM: 256-thread 128x128 blocks, BK=64, global_load_lds(16B) staging,
// XOR chunk swizzle (conflict-free, verified R2/R6 rocprof).
// ---------------------------------------------------------------------------

typedef __attribute__((ext_vector_type(8))) _Float16 half8;   // 4 VGPRs
typedef __attribute__((ext_vector_type(4))) float floatx4;

#define BK 64

static __device__ __forceinline__ unsigned short f2h(float f) {
    _Float16 h = (_Float16)f;          // RNE
    return *(unsigned short*)&h;
}

// async global->LDS, 16B per lane; LDS dst = wave-uniform base + lane*16
static __device__ __forceinline__ void gll16(const unsigned short* g,
                                             unsigned short* l) {
    __builtin_amdgcn_global_load_lds(
        (__attribute__((address_space(1))) void*)(g),
        (__attribute__((address_space(3))) void*)(l), 16, 0, 0);
}

// ---------------------------------------------------------------------------
// cast fp32 -> fp16 (elementwise, n % 4 == 0)
// ---------------------------------------------------------------------------
__global__ void cast_f16(const float* __restrict__ src,
                         unsigned short* __restrict__ dst, int n) {
    int i = (blockIdx.x * blockDim.x + threadIdx.x) * 4;
    if (i >= n) return;
    float4 f = *(const float4*)(src + i);
    *(ushort4*)(dst + i) =
        make_ushort4(f2h(f.x), f2h(f.y), f2h(f.z), f2h(f.w));
}

// ---------------------------------------------------------------------------
// Wz [R][C] fp32 -> T + z*R*C = Wz^T [C][R] fp16, z = 0,1,2 (Wk, Wq, Wv)
// ---------------------------------------------------------------------------
__global__ void splitT_w3(const float* __restrict__ W0,
                          const float* __restrict__ W1,
                          const float* __restrict__ W2,
                          unsigned short* __restrict__ T, int R, int C) {
    __shared__ float tile[32][33];
    const float* W = blockIdx.z == 0 ? W0 : (blockIdx.z == 1 ? W1 : W2);
    unsigned short* Tz = T + (size_t)blockIdx.z * R * C;
    int tx = threadIdx.x & 31, ty = threadIdx.x >> 5;   // 32 x 8
    int c0 = blockIdx.x * 32, r0 = blockIdx.y * 32;
#pragma unroll
    for (int j = 0; j < 32; j += 8)
        tile[ty + j][tx] = W[(long long)(r0 + ty + j) * C + c0 + tx];
    __syncthreads();
#pragma unroll
    for (int j = 0; j < 32; j += 8)
        Tz[(long long)(c0 + ty + j) * R + r0 + tx] = f2h(tile[tx][ty + j]);
}

// ---------------------------------------------------------------------------
// bias3[i] = concat(b0,b1,b2)[i], i < 3072
// ---------------------------------------------------------------------------
__global__ void bias_concat(const float* __restrict__ b0,
                            const float* __restrict__ b1,
                            const float* __restrict__ b2,
                            float* __restrict__ dst) {
    int i = blockIdx.x * blockDim.x + threadIdx.x;
    int s = i >> 10;
    const float* b = s == 0 ? b0 : (s == 1 ? b1 : b2);
    dst[i] = b[i & 1023];
}

// ---------------------------------------------------------------------------
// 16-bit transpose: src [z][R][C] -> dst [z][C][R]
// ---------------------------------------------------------------------------
__global__ void transpose_bf(const unsigned short* __restrict__ src,
                             unsigned short* __restrict__ dst, int R, int C) {
    __shared__ unsigned short tile[32][33];
    long long zs = (long long)blockIdx.z * R * C;
    int tx = threadIdx.x & 31, ty = threadIdx.x >> 5;
    int c0 = blockIdx.x * 32, r0 = blockIdx.y * 32;
#pragma unroll
    for (int j = 0; j < 32; j += 8)
        tile[ty + j][tx] = src[zs + (long long)(r0 + ty + j) * C + c0 + tx];
    __syncthreads();
#pragma unroll
    for (int j = 0; j < 32; j += 8)
        dst[zs + (long long)(c0 + ty + j) * R + r0 + tx] = tile[tx][ty + j];
}

// ---------------------------------------------------------------------------
// NT GEMM: C[M,N] = A[M,K] * B[N,K]^T (+bias[col]); fp16 in, fp32 acc.
// Block 128x128, 256 threads (4 waves, 2x2 grid of 64x64 wave tiles), BK=64.
// mode 0: fp32 -> Cf[rowg*N+colg]; mode 2: fp16 segmented -> Ch, where
//   segment = colg>>10, element Ch[seg*sC + rowg*1024 + (colg&1023)].
// LDS: unpadded [row][64] tiles (128B rows = full 32-bank span).
// XOR swizzle: chunk position p of row holds global chunk p ^ (row&7);
// b128 reads hit 8 distinct 16B positions per 16-lane group (conflict-free,
// verified R6 rocprof).
// ---------------------------------------------------------------------------
__global__ __launch_bounds__(256)
void gemm_nt(const unsigned short* __restrict__ A,
             const unsigned short* __restrict__ B,
             const float* __restrict__ bias,
             float* __restrict__ Cf,
             unsigned short* __restrict__ Ch,
             int mode, int M, int N, int K,
             long long sA, long long sB, long long sC) {
    __shared__ unsigned short smem[2 * 128 * BK];
    unsigned short* As = smem;
    unsigned short* Bs = smem + 128 * BK;

    const int tid = threadIdx.x;
    const int lane = tid & 63;
    const int wave = tid >> 6;          // 0..3
    const int quad = lane >> 4;
    const int l15 = lane & 15;
    const int wm = (wave & 1) * 64;
    const int wn = (wave >> 1) * 64;

    const long long zA = (long long)blockIdx.z * sA;
    const long long zB = (long long)blockIdx.z * sB;
    const long long zC = (long long)blockIdx.z * sC;
    const int m0 = blockIdx.y * 128;
    const int n0 = blockIdx.x * 128;

    // staging: wave w covers tile rows [32w, 32w+32) of A and B, 4 gll16 each
    // (8 rows x 128B per inst). lane i: row i>>3, position p=i&7 receives
    // global chunk p ^ (row&7).
    const int srow = wave * 32 + (lane >> 3);
    const int schunk8 = (((lane & 7) ^ ((lane >> 3) & 7)) << 3);
    const long long aoff = zA + (long long)(m0 + srow) * K + schunk8;
    const long long boff = zB + (long long)(n0 + srow) * K + schunk8;
    unsigned short* lA = As + (wave * 32) * BK;
    unsigned short* lB = Bs + (wave * 32) * BK;

    floatx4 zero = {0.f, 0.f, 0.f, 0.f};
    floatx4 acc[4][4];
#pragma unroll
    for (int i = 0; i < 4; ++i)
#pragma unroll
        for (int j = 0; j < 4; ++j) acc[i][j] = zero;

    for (int k0 = 0; k0 < K; k0 += BK) {
        __syncthreads();
#pragma unroll
        for (int j = 0; j < 4; ++j) {
            gll16(A + aoff + k0 + (long long)j * 8 * K, lA + j * 8 * BK);
            gll16(B + boff + k0 + (long long)j * 8 * K, lB + j * 8 * BK);
        }
        __syncthreads();

#pragma unroll
        for (int t = 0; t < 2; ++t) {      // two K=32 MFMA steps per BK=64
            half8 a[4], b[4];
#pragma unroll
            for (int mi = 0; mi < 4; ++mi) {
                int r = wm + mi * 16 + l15;
                int p = (t * 4 + quad) ^ (r & 7);
                a[mi] = *(const half8*)&As[r * BK + p * 8];
            }
#pragma unroll
            for (int ni = 0; ni < 4; ++ni) {
                int r = wn + ni * 16 + l15;
                int p = (t * 4 + quad) ^ (r & 7);
                b[ni] = *(const half8*)&Bs[r * BK + p * 8];
            }
#pragma unroll
            for (int mi = 0; mi < 4; ++mi)
#pragma unroll
                for (int ni = 0; ni < 4; ++ni)
                    acc[mi][ni] = __builtin_amdgcn_mfma_f32_16x16x32_f16(
                        a[mi], b[ni], acc[mi][ni], 0, 0, 0);
        }
    }

    // epilogue: C/D layout col=lane&15, row=quad*4+reg  [verified m89/m91]
#pragma unroll
    for (int mi = 0; mi < 4; ++mi)
#pragma unroll
        for (int ni = 0; ni < 4; ++ni) {
            int colg = n0 + wn + ni * 16 + l15;
            float bv = bias ? bias[colg] : 0.f;
#pragma unroll
            for (int r = 0; r < 4; ++r) {
                int rowg = m0 + wm + mi * 16 + quad * 4 + r;
                float v = acc[mi][ni][r] + bv;
                if (mode == 0) {
                    Cf[zC + (long long)rowg * N + colg] = v;
                } else {  // mode 2: segmented fp16 (k16|q16|v16 contiguous)
                    int seg = colg >> 10;
                    Ch[(long long)seg * sC + (long long)rowg * 1024 +
                       (colg & 1023)] = f2h(v);
                }
            }
        }
}

// ---------------------------------------------------------------------------
// row softmax: S [rows][cols] fp32 -> P fp16.  One block per row, cols=2048.
// ---------------------------------------------------------------------------
__global__ __launch_bounds__(256)
void softmax_rows(const float* __restrict__ S, unsigned short* __restrict__ P,
                  int cols) {
    __shared__ float red_m[4];
    __shared__ float red_s[4];
    const long long row = blockIdx.x;
    const float* s = S + row * cols;
    unsigned short* p = P + row * cols;
    const int tid = threadIdx.x;
    const int lane = tid & 63;
    const int wave = tid >> 6;

    float4 v0 = *(const float4*)(s + tid * 8);
    float4 v1 = *(const float4*)(s + tid * 8 + 4);
    float vals[8] = {v0.x, v0.y, v0.z, v0.w, v1.x, v1.y, v1.z, v1.w};

    float m = vals[0];
#pragma unroll
    for (int i = 1; i < 8; ++i) m = fmaxf(m, vals[i]);
#pragma unroll
    for (int off = 32; off >= 1; off >>= 1) m = fmaxf(m, __shfl_xor(m, off));
    if (lane == 0) red_m[wave] = m;
    __syncthreads();
    m = fmaxf(fmaxf(red_m[0], red_m[1]), fmaxf(red_m[2], red_m[3]));

    float e[8];
    float sum = 0.f;
#pragma unroll
    for (int i = 0; i < 8; ++i) {
        e[i] = __expf(vals[i] - m);
        sum += e[i];
    }
#pragma unroll
    for (int off = 32; off >= 1; off >>= 1) sum += __shfl_xor(sum, off);
    if (lane == 0) red_s[wave] = sum;
    __syncthreads();
    sum = red_s[0] + red_s[1] + red_s[2] + red_s[3];
    float inv = 1.0f / sum;

    unsigned short ob[8];
#pragma unroll
    for (int i = 0; i < 8; ++i) ob[i] = f2h(e[i] * inv);
    *(ushort4*)(p + tid * 8)     = make_ushort4(ob[0], ob[1], ob[2], ob[3]);
    *(ushort4*)(p + tid * 8 + 4) = make_ushort4(ob[4], ob[5], ob[6], ob[7]);
}

// ---------------------------------------------------------------------------
extern "C" void kernel_launch(void* const* d_in, const int* in_sizes, int n_in,
                              void* d_out, int out_size, void* d_ws,
                              size_t ws_size, hipStream_t stream) {
    const float* x  = (const float*)d_in[0];
    const float* Wk = (const float*)d_in[1];
    const float* bk = (const float*)d_in[2];
    const float* Wq = (const float*)d_in[3];
    const float* bq = (const float*)d_in[4];
    const float* Wv = (const float*)d_in[5];
    const float* bv = (const float*)d_in[6];
    float* out = (float*)d_out;

    const int Bb = 4, Ns = 2048, E = 1024, Aa = 1024;
    const int M = Bb * Ns;  // 8192

    char* p = (char*)d_ws;
    auto alloc = [&](size_t bytes) {
        char* r = p;
        p += (bytes + 255) & ~(size_t)255;
        return r;
    };
    const size_t MA = (size_t)M * Aa;          // 8.39M elems
    unsigned short* x16 = (unsigned short*)alloc(MA * 2);
    unsigned short* WT  = (unsigned short*)alloc((size_t)3 * E * Aa * 2);
    // k16,q16,v16 MUST be contiguous (segmented epilogue): MA*2 is a
    // multiple of 256, so alloc() inserts no padding.
    unsigned short* k16 = (unsigned short*)alloc(MA * 2);
    unsigned short* q16 = (unsigned short*)alloc(MA * 2);
    unsigned short* v16 = (unsigned short*)alloc(MA * 2);
    unsigned short* vT  = (unsigned short*)alloc(MA * 2);
    unsigned short* attn = (unsigned short*)alloc((size_t)M * Ns * 2);
    float* bias3 = (float*)alloc(3072 * 4);
    float* scores = (float*)alloc((size_t)Bb * Ns * Ns * 4);

    // 1. prep: x -> fp16; W^T fp16 x3; bias concat
    cast_f16<<<(int)(MA / 4 / 256), 256, 0, stream>>>(x, x16, (int)MA);
    splitT_w3<<<dim3(Aa / 32, E / 32, 3), 256, 0, stream>>>(Wk, Wq, Wv, WT, E, Aa);
    bias_concat<<<12, 256, 0, stream>>>(bk, bq, bv, bias3);

    // 2. fused projections: [k|q|v] = x16 @ [Wk|Wq|Wv]^T + bias3  (1-term)
    gemm_nt<<<dim3(3 * Aa / 128, M / 128, 1), 256, 0, stream>>>(
        x16, WT, bias3, nullptr, k16, 2, M, 3 * Aa, E, 0, 0, (long long)MA);

    // 3. scores[b,n,m] = k[b,n,:] . q[b,m,:]   (batched NT fp16, fp32 out)
    gemm_nt<<<dim3(Ns / 128, Ns / 128, Bb), 256, 0, stream>>>(
        k16, q16, nullptr, scores, nullptr, 0, Ns, Ns, Aa,
        (long long)Ns * Aa, (long long)Ns * Aa, (long long)Ns * Ns);

    // 4. softmax rows -> fp16 attn
    softmax_rows<<<M, 256, 0, stream>>>(scores, attn, Ns);

    // 5. v -> v^T (so attn@v is NT with contiguous K=m)
    transpose_bf<<<dim3(Aa / 32, Ns / 32, Bb), 256, 0, stream>>>(v16, vT, Ns, Aa);

    // 6. out[b,n,a] = sum_m attn[b,n,m] * vT[b,a,m]
    gemm_nt<<<dim3(Aa / 128, Ns / 128, Bb), 256, 0, stream>>>(
        attn, vT, nullptr, out, nullptr, 0, Ns, Aa, Ns,
        (long long)Ns * Ns, (long long)Aa * Ns, (long long)Ns * Aa);
}

// Round 8
// 282.506 us; speedup vs baseline: 1.5966x; 1.0710x over previous
//
#include <hip/hip_runtime.h>

// ---------------------------------------------------------------------------
// SelfAttention: out = softmax((x@Wk+bk) @ (x@Wq+bq)^T) @ (x@Wv+bv)
// B=4, N=2048, E=A=1024, fp32 in/out.
// R8: 1-term fp16 pipeline (absmax 0.081, frozen). Changes vs R7:
//  - dispatches 8->5: prep (cast+W^T+bias) fused; softmax+v-transpose fused.
//  - GEMM wave tile 128x64 (block 256x128, acc[8][4]) for proj & scores:
//    64 MFMA / 24 ds_read_b128 per barrier = R6's 888 TF profile, 1-term.
//    PV keeps 128x128 blocks (TM=256 would leave only 256 blocks).
// ---------------------------------------------------------------------------

typedef __attribute__((ext_vector_type(8))) _Float16 half8;   // 4 VGPRs
typedef __attribute__((ext_vector_type(4))) float floatx4;

#define BK 64

static __device__ __forceinline__ unsigned short f2h(float f) {
    _Float16 h = (_Float16)f;          // RNE
    return *(unsigned short*)&h;
}

// async global->LDS, 16B per lane; LDS dst = wave-uniform base + lane*16
static __device__ __forceinline__ void gll16(const unsigned short* g,
                                             unsigned short* l) {
    __builtin_amdgcn_global_load_lds(
        (__attribute__((address_space(1))) void*)(g),
        (__attribute__((address_space(3))) void*)(l), 16, 0, 0);
}

// ---------------------------------------------------------------------------
// prep: blocks 0..8191 cast x -> fp16; 8192..11263 transpose W0..2 -> fp16;
// 11264..11275 bias concat.  (x: MA=8.39M elems, W: 1024x1024 each)
// ---------------------------------------------------------------------------
__global__ __launch_bounds__(256)
void prep(const float* __restrict__ x,
          const float* __restrict__ W0, const float* __restrict__ W1,
          const float* __restrict__ W2,
          const float* __restrict__ b0, const float* __restrict__ b1,
          const float* __restrict__ b2,
          unsigned short* __restrict__ x16, unsigned short* __restrict__ WT,
          float* __restrict__ bias3) {
    __shared__ float tile[32][33];
    const int bid = blockIdx.x;
    if (bid < 8192) {
        int i = bid * 1024 + threadIdx.x * 4;
        float4 f = *(const float4*)(x + i);
        *(ushort4*)(x16 + i) =
            make_ushort4(f2h(f.x), f2h(f.y), f2h(f.z), f2h(f.w));
    } else if (bid < 11264) {
        int wz = bid - 8192;
        int z = wz >> 10;                    // which W (1024 tiles each)
        int t = wz & 1023;
        const float* W = z == 0 ? W0 : (z == 1 ? W1 : W2);
        unsigned short* Tz = WT + (size_t)z * 1024 * 1024;
        int c0 = (t & 31) * 32, r0 = (t >> 5) * 32;
        int tx = threadIdx.x & 31, ty = threadIdx.x >> 5;
#pragma unroll
        for (int j = 0; j < 32; j += 8)
            tile[ty + j][tx] = W[(r0 + ty + j) * 1024 + c0 + tx];
        __syncthreads();
#pragma unroll
        for (int j = 0; j < 32; j += 8)
            Tz[(c0 + ty + j) * 1024 + r0 + tx] = f2h(tile[tx][ty + j]);
    } else {
        int i = (bid - 11264) * 256 + threadIdx.x;   // 12*256 = 3072
        int s = i >> 10;
        const float* b = s == 0 ? b0 : (s == 1 ? b1 : b2);
        bias3[i] = b[i & 1023];
    }
}

// ---------------------------------------------------------------------------
// NT GEMM: C[M,N] = A[M,K] * B[N,K]^T (+bias[col]); fp16 in, fp32 acc.
// Block TM x 128, 256 threads (4 waves, 2x2; wave tile TM/2 x 64), BK=64.
// TM=256: 64 MFMA vs 24 ds_read_b128 per wave per barrier (MFMA-bound).
// TM=128: R7 config (for PV where the grid would otherwise be too small).
// mode 0: fp32 -> Cf[rowg*N+colg]; mode 2: fp16 segmented -> Ch with
//   segment = colg>>10, Ch[seg*sC + rowg*1024 + (colg&1023)].
// LDS: unpadded [row][64] tiles; XOR chunk swizzle (position p of row r
// holds global chunk p ^ (r&7)) -- conflict-free, verified R6/R7 rocprof.
// ---------------------------------------------------------------------------
template <int TM>
__global__ __launch_bounds__(256, 2)
void gemm_nt(const unsigned short* __restrict__ A,
             const unsigned short* __restrict__ B,
             const float* __restrict__ bias,
             float* __restrict__ Cf,
             unsigned short* __restrict__ Ch,
             int mode, int M, int N, int K,
             long long sA, long long sB, long long sC) {
    constexpr int WM = TM / 2;       // wave tile rows
    constexpr int MI = WM / 16;      // acc row-tiles per wave
    __shared__ unsigned short smem[(TM + 128) * BK];
    unsigned short* As = smem;                  // TM x BK
    unsigned short* Bs = smem + TM * BK;        // 128 x BK

    const int tid = threadIdx.x;
    const int lane = tid & 63;
    const int wave = tid >> 6;          // 0..3
    const int quad = lane >> 4;
    const int l15 = lane & 15;
    const int wm = (wave & 1) * WM;
    const int wn = (wave >> 1) * 64;

    const long long zA = (long long)blockIdx.z * sA;
    const long long zB = (long long)blockIdx.z * sB;
    const long long zC = (long long)blockIdx.z * sC;
    const int m0 = blockIdx.y * TM;
    const int n0 = blockIdx.x * 128;

    // staging: lane i covers row i>>3; position p=i&7 gets chunk p ^ (row&7)
    const int arow = wave * (TM / 4) + (lane >> 3);
    const int brow = wave * 32 + (lane >> 3);
    const int schunk8 = (((lane & 7) ^ ((lane >> 3) & 7)) << 3);
    const long long aoff = zA + (long long)(m0 + arow) * K + schunk8;
    const long long boff = zB + (long long)(n0 + brow) * K + schunk8;
    unsigned short* lA = As + (wave * (TM / 4)) * BK;
    unsigned short* lB = Bs + (wave * 32) * BK;

    floatx4 zero = {0.f, 0.f, 0.f, 0.f};
    floatx4 acc[MI][4];
#pragma unroll
    for (int i = 0; i < MI; ++i)
#pragma unroll
        for (int j = 0; j < 4; ++j) acc[i][j] = zero;

    for (int k0 = 0; k0 < K; k0 += BK) {
        __syncthreads();
#pragma unroll
        for (int j = 0; j < TM / 32; ++j)
            gll16(A + aoff + k0 + (long long)j * 8 * K, lA + j * 8 * BK);
#pragma unroll
        for (int j = 0; j < 4; ++j)
            gll16(B + boff + k0 + (long long)j * 8 * K, lB + j * 8 * BK);
        __syncthreads();

#pragma unroll
        for (int t = 0; t < 2; ++t) {      // two K=32 MFMA steps per BK=64
            half8 a[MI], b[4];
#pragma unroll
            for (int mi = 0; mi < MI; ++mi) {
                int r = wm + mi * 16 + l15;
                int p = (t * 4 + quad) ^ (r & 7);
                a[mi] = *(const half8*)&As[r * BK + p * 8];
            }
#pragma unroll
            for (int ni = 0; ni < 4; ++ni) {
                int r = wn + ni * 16 + l15;
                int p = (t * 4 + quad) ^ (r & 7);
                b[ni] = *(const half8*)&Bs[r * BK + p * 8];
            }
#pragma unroll
            for (int mi = 0; mi < MI; ++mi)
#pragma unroll
                for (int ni = 0; ni < 4; ++ni)
                    acc[mi][ni] = __builtin_amdgcn_mfma_f32_16x16x32_f16(
                        a[mi], b[ni], acc[mi][ni], 0, 0, 0);
        }
    }

    // epilogue: C/D layout col=lane&15, row=quad*4+reg  [verified m89/m91]
#pragma unroll
    for (int mi = 0; mi < MI; ++mi)
#pragma unroll
        for (int ni = 0; ni < 4; ++ni) {
            int colg = n0 + wn + ni * 16 + l15;
            float bv = bias ? bias[colg] : 0.f;
#pragma unroll
            for (int r = 0; r < 4; ++r) {
                int rowg = m0 + wm + mi * 16 + quad * 4 + r;
                float v = acc[mi][ni][r] + bv;
                if (mode == 0) {
                    Cf[zC + (long long)rowg * N + colg] = v;
                } else {  // mode 2: segmented fp16 (k16|q16|v16 contiguous)
                    int seg = colg >> 10;
                    Ch[(long long)seg * sC + (long long)rowg * 1024 +
                       (colg & 1023)] = f2h(v);
                }
            }
        }
}

// ---------------------------------------------------------------------------
// fused: blocks 0..8191 = row softmax (scores fp32 [8192][2048] -> attn fp16)
//        blocks 8192..16383 = v16 [z][2048][1024] -> vT [z][1024][2048]
// ---------------------------------------------------------------------------
__global__ __launch_bounds__(256)
void softmax_vT(const float* __restrict__ S, unsigned short* __restrict__ P,
                const unsigned short* __restrict__ v,
                unsigned short* __restrict__ vT) {
    __shared__ float red_m[4];
    __shared__ float red_s[4];
    __shared__ unsigned short tile[32][33];
    const int bid = blockIdx.x;
    const int tid = threadIdx.x;

    if (bid < 8192) {
        const float* s = S + (long long)bid * 2048;
        unsigned short* p = P + (long long)bid * 2048;
        const int lane = tid & 63;
        const int wave = tid >> 6;

        float4 v0 = *(const float4*)(s + tid * 8);
        float4 v1 = *(const float4*)(s + tid * 8 + 4);
        float vals[8] = {v0.x, v0.y, v0.z, v0.w, v1.x, v1.y, v1.z, v1.w};

        float m = vals[0];
#pragma unroll
        for (int i = 1; i < 8; ++i) m = fmaxf(m, vals[i]);
#pragma unroll
        for (int off = 32; off >= 1; off >>= 1)
            m = fmaxf(m, __shfl_xor(m, off));
        if (lane == 0) red_m[wave] = m;
        __syncthreads();
        m = fmaxf(fmaxf(red_m[0], red_m[1]), fmaxf(red_m[2], red_m[3]));

        float e[8];
        float sum = 0.f;
#pragma unroll
        for (int i = 0; i < 8; ++i) {
            e[i] = __expf(vals[i] - m);
            sum += e[i];
        }
#pragma unroll
        for (int off = 32; off >= 1; off >>= 1) sum += __shfl_xor(sum, off);
        if (lane == 0) red_s[wave] = sum;
        __syncthreads();
        sum = red_s[0] + red_s[1] + red_s[2] + red_s[3];
        float inv = 1.0f / sum;

        unsigned short ob[8];
#pragma unroll
        for (int i = 0; i < 8; ++i) ob[i] = f2h(e[i] * inv);
        *(ushort4*)(p + tid * 8)     = make_ushort4(ob[0], ob[1], ob[2], ob[3]);
        *(ushort4*)(p + tid * 8 + 4) = make_ushort4(ob[4], ob[5], ob[6], ob[7]);
    } else {
        int t = bid - 8192;
        int z = t >> 11;                 // batch
        int rest = t & 2047;             // 32 col-tiles x 64 row-tiles
        int c0 = (rest & 31) * 32;
        int r0 = (rest >> 5) * 32;
        long long zs = (long long)z * 2048 * 1024;
        int tx = tid & 31, ty = tid >> 5;
#pragma unroll
        for (int j = 0; j < 32; j += 8)
            tile[ty + j][tx] = v[zs + (long long)(r0 + ty + j) * 1024 + c0 + tx];
        __syncthreads();
#pragma unroll
        for (int j = 0; j < 32; j += 8)
            vT[zs + (long long)(c0 + ty + j) * 2048 + r0 + tx] =
                tile[tx][ty + j];
    }
}

// ---------------------------------------------------------------------------
extern "C" void kernel_launch(void* const* d_in, const int* in_sizes, int n_in,
                              void* d_out, int out_size, void* d_ws,
                              size_t ws_size, hipStream_t stream) {
    const float* x  = (const float*)d_in[0];
    const float* Wk = (const float*)d_in[1];
    const float* bk = (const float*)d_in[2];
    const float* Wq = (const float*)d_in[3];
    const float* bq = (const float*)d_in[4];
    const float* Wv = (const float*)d_in[5];
    const float* bv = (const float*)d_in[6];
    float* out = (float*)d_out;

    const int Bb = 4, Ns = 2048, E = 1024, Aa = 1024;
    const int M = Bb * Ns;  // 8192

    char* p = (char*)d_ws;
    auto alloc = [&](size_t bytes) {
        char* r = p;
        p += (bytes + 255) & ~(size_t)255;
        return r;
    };
    const size_t MA = (size_t)M * Aa;          // 8.39M elems
    unsigned short* x16 = (unsigned short*)alloc(MA * 2);
    unsigned short* WT  = (unsigned short*)alloc((size_t)3 * E * Aa * 2);
    // k16,q16,v16 MUST be contiguous (segmented epilogue): MA*2 is a
    // multiple of 256, so alloc() inserts no padding.
    unsigned short* k16 = (unsigned short*)alloc(MA * 2);
    unsigned short* q16 = (unsigned short*)alloc(MA * 2);
    unsigned short* v16 = (unsigned short*)alloc(MA * 2);
    unsigned short* vT  = (unsigned short*)alloc(MA * 2);
    unsigned short* attn = (unsigned short*)alloc((size_t)M * Ns * 2);
    float* bias3 = (float*)alloc(3072 * 4);
    float* scores = (float*)alloc((size_t)Bb * Ns * Ns * 4);

    // 1. prep: x->fp16, W^T x3, bias concat (one dispatch)
    prep<<<11276, 256, 0, stream>>>(x, Wk, Wq, Wv, bk, bq, bv, x16, WT, bias3);

    // 2. fused projections: [k|q|v] = x16 @ [Wk|Wq|Wv]^T + bias3
    gemm_nt<256><<<dim3(3 * Aa / 128, M / 256, 1), 256, 0, stream>>>(
        x16, WT, bias3, nullptr, k16, 2, M, 3 * Aa, E, 0, 0, (long long)MA);

    // 3. scores[b,n,m] = k[b,n,:] . q[b,m,:]   (batched NT fp16, fp32 out)
    gemm_nt<256><<<dim3(Ns / 128, Ns / 256, Bb), 256, 0, stream>>>(
        k16, q16, nullptr, scores, nullptr, 0, Ns, Ns, Aa,
        (long long)Ns * Aa, (long long)Ns * Aa, (long long)Ns * Ns);

    // 4. softmax rows -> fp16 attn; v -> v^T (one dispatch)
    softmax_vT<<<16384, 256, 0, stream>>>(scores, attn, v16, vT);

    // 5. out[b,n,a] = sum_m attn[b,n,m] * vT[b,a,m]
    gemm_nt<128><<<dim3(Aa / 128, Ns / 128, Bb), 256, 0, stream>>>(
        attn, vT, nullptr, out, nullptr, 0, Ns, Aa, Ns,
        (long long)Ns * Ns, (long long)Aa * Ns, (long long)Ns * Aa);
}